// Round 5
// baseline (1949.233 us; speedup 1.0000x reference)
//
#include <hip/hip_runtime.h>
#include <stdint.h>

// LSTM: B=65536, T=28, IN=28, H=128. Final hidden [B,H] output.
// Block = 32 batch rows x 28 timesteps, 4 waves. Wave w owns output columns
// [32w,32w+32) for ALL FOUR gates -> gates stay in fp32 registers.
// Weights: packed bf16 lane-interleaved [wv][ks][lane][8frag x 16B], streamed
// from L2, loaded ONCE per step (hoisted over both mt row-tiles).
// ROUND 5: accumulators pinned to AGPRs via empty-asm "+a" constraints.
// Diagnosis: rounds 2-4 all reported VGPR=128 with ~700 MB scratch traffic
// regardless of A-frag trims -> the 64 acc regs were living in the ARCH file
// (AGPRs unused), making K-loop peak ~185 arch regs -> ~60 spilled. Pinning
// acc to AGPRs drops arch demand to ~120 (w 64 + a 16 + c 16 + bias 8 +
// temps) -> spill-free at the allocator's 128 target, AGPR side holds 64.

#define T_STEPS   28
#define HDIM      128
#define KIN       156            // H + IN
#define KPAD      160            // K padded for packed weights
#define MB        32             // batch rows per block
#define KSTEPS    5              // K=160: 4x32 (h) + 1x32 (x: 28 real + 4 pad)
#define HLDS_ST   136            // h_lds row stride in shorts (128 + 8 pad)
#define XLDS_ST   40             // x_lds row stride in shorts (32 + 8 pad)

#define WS_WOFF   1024                       // byte offset of packed weights in d_ws
#define WS_BOFF   (1024 + 4*HDIM*KPAD*2)     // byte offset of fp32 biases

typedef __attribute__((ext_vector_type(8))) short  short8;
typedef __attribute__((ext_vector_type(4))) float  floatx4;

union Frag { short8 f; uint2 u2[2]; unsigned short s[8]; };
union Pk4  { uint2 u2; unsigned short s[4]; };

__device__ __forceinline__ float bf2f(unsigned short v) {
    union { uint32_t u; float f; } c; c.u = ((uint32_t)v) << 16; return c.f;
}
__device__ __forceinline__ unsigned short f2bf(float x) {
    union { float f; uint32_t u; } c; c.f = x;          // RNE bf16 (finite inputs)
    return (unsigned short)((c.u + 0x7FFFu + ((c.u >> 16) & 1u)) >> 16);
}
__device__ __forceinline__ float fast_rcp(float x) { return __builtin_amdgcn_rcpf(x); }
// NaN-free at extremes: exp->inf => rcp->0; exp->0 => rcp(1)=1.
__device__ __forceinline__ float sigm(float x)   { return fast_rcp(1.0f + __expf(-x)); }
__device__ __forceinline__ float tanh_f(float x) {
    float e = __expf(2.0f * x);
    return 1.0f - 2.0f * fast_rcp(e + 1.0f);
}

// bf16 |W_f| <= 0.08 -> exponent field <= 123 always. fp32 read as shorts:
// mantissa halves ~uniform -> exponent field >= 127 with p~0.5/short.
__global__ void detect_dtype(const unsigned short* __restrict__ wf, int* __restrict__ flag) {
    const int lane = threadIdx.x;
    bool big = false;
    #pragma unroll
    for (int i = 0; i < 4; ++i) {
        unsigned e = (wf[lane * 4 + i] >> 7) & 0xFFu;
        if (e >= 127u) big = true;
    }
    const int isfp32 = __any(big) ? 1 : 0;
    if (lane == 0) *flag = isfp32;
}

// One-shot: pack W[4][128][156] -> bf16 lane-interleaved fragments:
//   idx = ((((wv*5 + ks)*64 + lane)*8 + fi)*8 + e)
//   fi = g*2+n2; value = W[g][wv*32 + n2*16 + (lane&15)][ks*32 + (lane>>4)*8 + e]
// (zero beyond K=156). Biases -> fp32 [4][128]. Grid: 320 x 256 = 81920 shorts.
template <bool FP32>
__global__ void pack_weights(const void* __restrict__ Wf_, const void* __restrict__ bf_,
                             const void* __restrict__ Wi_, const void* __restrict__ bi_,
                             const void* __restrict__ Wc_, const void* __restrict__ bc_,
                             const void* __restrict__ Wo_, const void* __restrict__ bo_,
                             void* __restrict__ ws, const int* __restrict__ flag)
{
    if (*flag != (FP32 ? 1 : 0)) return;
    unsigned short* wpk = (unsigned short*)((char*)ws + WS_WOFF);
    float*          bpk = (float*)((char*)ws + WS_BOFF);

    const int gid = blockIdx.x * 256 + threadIdx.x;        // 0..81919
    const int e   = gid & 7;
    const int fi  = (gid >> 3) & 7;
    const int ln  = (gid >> 6) & 63;
    const int blk = gid >> 12;                             // wv*5 + ks
    const int ks  = blk % KSTEPS;
    const int wv  = blk / KSTEPS;
    const int g   = fi >> 1, n2 = fi & 1;
    const int q   = ln >> 4, cc = ln & 15;
    const int n   = wv * 32 + n2 * 16 + cc;
    const int k   = ks * 32 + q * 8 + e;
    const void* Wg = (g == 0) ? Wf_ : (g == 1) ? Wi_ : (g == 2) ? Wc_ : Wo_;

    unsigned short v = 0;
    if (k < KIN) {
        if constexpr (FP32) v = f2bf(((const float*)Wg)[n * KIN + k]);
        else                v = ((const unsigned short*)Wg)[n * KIN + k];
    }
    wpk[gid] = v;

    if (gid < 4 * HDIM) {
        const int gg = gid >> 7, nn = gid & 127;
        const void* bg = (gg == 0) ? bf_ : (gg == 1) ? bi_ : (gg == 2) ? bc_ : bo_;
        if constexpr (FP32) bpk[gid] = ((const float*)bg)[nn];
        else                bpk[gid] = bf2f(((const unsigned short*)bg)[nn]);
    }
}

template <bool FP32>
__global__ __launch_bounds__(256)
__attribute__((amdgpu_waves_per_eu(2, 2)))
void lstm_fused(const void* __restrict__ x_, const void* __restrict__ ws,
                void* __restrict__ out_, const int* __restrict__ flag)
{
    if (*flag != (FP32 ? 1 : 0)) return;   // wrong-dtype variant: uniform exit

    __shared__ __align__(16) unsigned short h_lds[2][MB * HLDS_ST];   // 17408 B
    __shared__ __align__(16) unsigned short x_lds[2][MB * XLDS_ST];   //  5120 B

    const int tid  = threadIdx.x;
    const int wv   = tid >> 6;
    const int lane = tid & 63;
    const int q    = lane >> 4;    // quad
    const int cc   = lane & 15;
    const int b0   = blockIdx.x * MB;

    const unsigned short* wpk = (const unsigned short*)((const char*)ws + WS_WOFF);
    const float*          bpk = (const float*)((const char*)ws + WS_BOFF);
    // per-lane fragment base: 64 shorts (8 frags x 16B) per lane; 4096 shorts per ks
    const unsigned short* wb  = wpk + ((size_t)(wv * KSTEPS) * 64 + lane) * 64;

    float bias_r[4][2];
    #pragma unroll
    for (int g = 0; g < 4; ++g)
        #pragma unroll
        for (int n2 = 0; n2 < 2; ++n2)
            bias_r[g][n2] = bpk[g * HDIM + wv * 32 + n2 * 16 + cc];

    // zero h buf0 (h0=0) and x pads (shorts 28..39 of each row stay 0 forever)
    for (int i = tid; i < MB * HLDS_ST; i += 256) h_lds[0][i] = 0;
    for (int i = tid; i < MB * XLDS_ST; i += 256) { x_lds[0][i] = 0; x_lds[1][i] = 0; }

    // x staging: 7 threads/row, 4 elems each -> 28 elems/row
    auto stage_x = [&](int ts, int buf) {
        if (tid < 224) {
            const int row = tid / 7, sub = tid % 7;
            const size_t off = (size_t)(b0 + row) * (T_STEPS * 28) + ts * 28 + sub * 4;
            Pk4 pk;
            if constexpr (FP32) {
                float4 v = *(const float4*)((const float*)x_ + off);
                pk.s[0] = f2bf(v.x); pk.s[1] = f2bf(v.y);
                pk.s[2] = f2bf(v.z); pk.s[3] = f2bf(v.w);
            } else {
                pk.u2 = *(const uint2*)((const unsigned short*)x_ + off);
            }
            *(uint2*)&x_lds[buf][row * XLDS_ST + sub * 4] = pk.u2;
        }
    };
    stage_x(0, 0);

    float c_st[2][2][4];                       // [mt][n2][r] cell state, fp32
    #pragma unroll
    for (int mt = 0; mt < 2; ++mt)
        #pragma unroll
        for (int n2 = 0; n2 < 2; ++n2)
            #pragma unroll
            for (int r = 0; r < 4; ++r) c_st[mt][n2][r] = 0.0f;

    __syncthreads();

    int cur = 0;
    #pragma unroll 1
    for (int t = 0; t < T_STEPS; ++t) {
        // prefetch next x tile into the other buffer (no reader until next step)
        if (t + 1 < T_STEPS) stage_x(t + 1, cur ^ 1);

        // ---- issue W group ks=0 early (hides L2 latency under A-loads/init)
        Frag w0[8], w1[8];
        #pragma unroll
        for (int fi = 0; fi < 8; ++fi)
            w0[fi].f = *(const short8*)(wb + fi * 8);

        // ---- A fragments: parity double-buffer, loaded per-ks (16 regs live)
        Frag a[2][2];                          // [ks parity][mt]
        #pragma unroll
        for (int mt = 0; mt < 2; ++mt)
            a[0][mt].f = *(const short8*)&h_lds[cur][(mt * 16 + cc) * HLDS_ST + q * 8];

        floatx4 acc[2][4][2];
        #pragma unroll
        for (int mt = 0; mt < 2; ++mt)
            #pragma unroll
            for (int g = 0; g < 4; ++g)
                #pragma unroll
                for (int n2 = 0; n2 < 2; ++n2) {
                    const float bv = bias_r[g][n2];
                    acc[mt][g][n2] = (floatx4){bv, bv, bv, bv};
                }

        // ---- pin accumulators to the AGPR file: arch VGPRs stay <=128, no
        // spill. Zero-instruction asm; forces reg class for the MFMA tie-chain.
        #pragma unroll
        for (int mt = 0; mt < 2; ++mt)
            #pragma unroll
            for (int g = 0; g < 4; ++g)
                #pragma unroll
                for (int n2 = 0; n2 < 2; ++n2)
                    asm volatile("" : "+a"(acc[mt][g][n2]));

        // ---- K loop: weights loaded ONCE per group, feed both mt tiles.
        // Both w and a are 1-deep double-buffered (statically resolved).
        #pragma unroll
        for (int ks = 0; ks < KSTEPS; ++ks) {
            Frag* wc = (ks & 1) ? w1 : w0;
            Frag* wn = (ks & 1) ? w0 : w1;
            Frag* ac = a[ks & 1];
            Frag* an = a[(ks + 1) & 1];
            if (ks + 1 < KSTEPS) {
                #pragma unroll
                for (int fi = 0; fi < 8; ++fi)
                    wn[fi].f = *(const short8*)(wb + (ks + 1) * 4096 + fi * 8);
                #pragma unroll
                for (int mt = 0; mt < 2; ++mt) {
                    if (ks + 1 < 4)
                        an[mt].f = *(const short8*)&h_lds[cur][(mt * 16 + cc) * HLDS_ST + (ks + 1) * 32 + q * 8];
                    else
                        an[mt].f = *(const short8*)&x_lds[cur][(mt * 16 + cc) * XLDS_ST + q * 8];
                }
            }
            #pragma unroll
            for (int g = 0; g < 4; ++g)
                #pragma unroll
                for (int n2 = 0; n2 < 2; ++n2) {
                    acc[0][g][n2] = __builtin_amdgcn_mfma_f32_16x16x32_bf16(
                        ac[0].f, wc[g * 2 + n2].f, acc[0][g][n2], 0, 0, 0);
                    acc[1][g][n2] = __builtin_amdgcn_mfma_f32_16x16x32_bf16(
                        ac[1].f, wc[g * 2 + n2].f, acc[1][g][n2], 0, 0, 0);
                }
        }

        // ---- re-pin at loop exit so the whole MFMA chain stays AGPR-resident
        #pragma unroll
        for (int mt = 0; mt < 2; ++mt)
            #pragma unroll
            for (int g = 0; g < 4; ++g)
                #pragma unroll
                for (int n2 = 0; n2 < 2; ++n2)
                    asm volatile("" : "+a"(acc[mt][g][n2]));

        // ---- gates in-register: activations + c,h update, write h to next buf
        #pragma unroll
        for (int mt = 0; mt < 2; ++mt)
            #pragma unroll
            for (int n2 = 0; n2 < 2; ++n2) {
                const int j = wv * 32 + n2 * 16 + cc;
                #pragma unroll
                for (int r = 0; r < 4; ++r) {
                    const float fv = sigm(acc[mt][0][n2][r]);
                    const float iv = sigm(acc[mt][1][n2][r]);
                    const float nv = tanh_f(acc[mt][2][n2][r]);
                    const float ov = sigm(acc[mt][3][n2][r]);
                    const float cn = c_st[mt][n2][r] * fv + iv * nv;
                    c_st[mt][n2][r] = cn;
                    const float hv = ov * tanh_f(cn);
                    const int mrow = mt * 16 + q * 4 + r;
                    h_lds[cur ^ 1][mrow * HLDS_ST + j] = f2bf(hv);
                    if (t == T_STEPS - 1) {
                        const size_t oi = (size_t)(b0 + mrow) * HDIM + j;
                        if constexpr (FP32) ((float*)out_)[oi] = hv;
                        else                ((unsigned short*)out_)[oi] = f2bf(hv);
                    }
                }
            }
        __syncthreads();     // single barrier: publishes h[cur^1] and x[cur^1]
        cur ^= 1;
    }
}

extern "C" void kernel_launch(void* const* d_in, const int* in_sizes, int n_in,
                              void* d_out, int out_size, void* d_ws, size_t ws_size,
                              hipStream_t stream) {
    int* flag = (int*)d_ws;
    detect_dtype<<<dim3(1), dim3(64), 0, stream>>>((const unsigned short*)d_in[1], flag);

    pack_weights<false><<<dim3(320), dim3(256), 0, stream>>>(
        d_in[1], d_in[2], d_in[3], d_in[4], d_in[5], d_in[6], d_in[7], d_in[8], d_ws, flag);
    pack_weights<true><<<dim3(320), dim3(256), 0, stream>>>(
        d_in[1], d_in[2], d_in[3], d_in[4], d_in[5], d_in[6], d_in[7], d_in[8], d_ws, flag);

    lstm_fused<false><<<dim3(65536 / MB), dim3(256), 0, stream>>>(d_in[0], d_ws, d_out, flag);
    lstm_fused<true><<<dim3(65536 / MB), dim3(256), 0, stream>>>(d_in[0], d_ws, d_out, flag);
}

// Round 6
// 682.666 us; speedup vs baseline: 2.8553x; 2.8553x over previous
//
#include <hip/hip_runtime.h>
#include <stdint.h>

// LSTM: B=65536, T=28, IN=28, H=128. Final hidden [B,H] output.
// ROUND 6: 8-wave (512-thread) blocks, wave w owns 16 output columns for all
// 4 gates. Weights PERSISTENT in registers (4g x 5ks x 4 VGPR = 80) -> zero
// in-loop global traffic (R1's 18 GB L2 weight stream @ ~84% of L2 ceiling is
// gone). Cell state c lives in LDS (fp32, stride 132 -> conflict-free),
// freeing 16 VGPRs; per-mt accumulation (acc=16 regs). Total live ~125 ->
// __launch_bounds__(512,4) pins a 128-reg budget = 4 waves/SIMD = 16 waves/CU,
// double every previous round's occupancy.
// Lesson from R5: NO volatile-asm register-class pins (they serialize the
// scheduler; 2.3x regression despite eliminating spill).

#define T_STEPS   28
#define HDIM      128
#define KIN       156            // H + IN
#define MB        32             // batch rows per block
#define KSTEPS    5              // K=160: 4x32 (h) + 1x32 (x: 28 real + 4 pad)
#define HLDS_ST   136            // h_lds row stride in shorts (128 + 8 pad)
#define XLDS_ST   40             // x_lds row stride in shorts (32 + 8 pad)
#define CLDS_ST   132            // c_lds row stride in floats (128 + 4 pad)

#define WS_WOFF   1024                       // byte offset of packed weights in d_ws
#define WS_BOFF   (1024 + 4*HDIM*160*2)      // byte offset of fp32 biases

typedef __attribute__((ext_vector_type(8))) short  short8;
typedef __attribute__((ext_vector_type(4))) float  floatx4;

union Frag { short8 f; uint2 u2[2]; unsigned short s[8]; };
union Pk4  { uint2 u2; unsigned short s[4]; };

__device__ __forceinline__ float bf2f(unsigned short v) {
    union { uint32_t u; float f; } c; c.u = ((uint32_t)v) << 16; return c.f;
}
__device__ __forceinline__ unsigned short f2bf(float x) {
    union { float f; uint32_t u; } c; c.f = x;          // RNE bf16 (finite inputs)
    return (unsigned short)((c.u + 0x7FFFu + ((c.u >> 16) & 1u)) >> 16);
}
__device__ __forceinline__ float fast_rcp(float x) { return __builtin_amdgcn_rcpf(x); }
// NaN-free at extremes: exp->inf => rcp->0; exp->0 => rcp(1)=1.
__device__ __forceinline__ float sigm(float x)   { return fast_rcp(1.0f + __expf(-x)); }
__device__ __forceinline__ float tanh_f(float x) {
    float e = __expf(2.0f * x);
    return 1.0f - 2.0f * fast_rcp(e + 1.0f);
}

// bf16 |W_f| <= 0.08 -> exponent field <= 123 always. fp32 read as shorts:
// mantissa halves ~uniform -> exponent field >= 127 with p~0.5/short.
__global__ void detect_dtype(const unsigned short* __restrict__ wf, int* __restrict__ flag) {
    const int lane = threadIdx.x;
    bool big = false;
    #pragma unroll
    for (int i = 0; i < 4; ++i) {
        unsigned e = (wf[lane * 4 + i] >> 7) & 0xFFu;
        if (e >= 127u) big = true;
    }
    const int isfp32 = __any(big) ? 1 : 0;
    if (lane == 0) *flag = isfp32;
}

// One-shot: pack W[4][128][156] -> bf16 per-(wave,ks,lane) fragments:
//   chunk = wv*5+ks (2048 shorts each); within: lane(6b), g(2b), e(3b)
//   value = W[g][wv*16 + (lane&15)][ks*32 + (lane>>4)*8 + e]  (0 beyond K=156)
// Biases -> fp32 [4][128]. Grid: 320 x 256 = 81920 shorts.
template <bool FP32>
__global__ void pack_weights(const void* __restrict__ Wf_, const void* __restrict__ bf_,
                             const void* __restrict__ Wi_, const void* __restrict__ bi_,
                             const void* __restrict__ Wc_, const void* __restrict__ bc_,
                             const void* __restrict__ Wo_, const void* __restrict__ bo_,
                             void* __restrict__ ws, const int* __restrict__ flag)
{
    if (*flag != (FP32 ? 1 : 0)) return;
    unsigned short* wpk = (unsigned short*)((char*)ws + WS_WOFF);
    float*          bpk = (float*)((char*)ws + WS_BOFF);

    const int gid = blockIdx.x * 256 + threadIdx.x;        // 0..81919
    const int e   = gid & 7;
    const int g   = (gid >> 3) & 3;
    const int ln  = (gid >> 5) & 63;
    const int blk = gid >> 11;                             // wv*5 + ks, 0..39
    const int ks  = blk % KSTEPS;
    const int wv  = blk / KSTEPS;
    const int n   = wv * 16 + (ln & 15);
    const int k   = ks * 32 + (ln >> 4) * 8 + e;
    const void* Wg = (g == 0) ? Wf_ : (g == 1) ? Wi_ : (g == 2) ? Wc_ : Wo_;

    unsigned short v = 0;
    if (k < KIN) {
        if constexpr (FP32) v = f2bf(((const float*)Wg)[n * KIN + k]);
        else                v = ((const unsigned short*)Wg)[n * KIN + k];
    }
    wpk[gid] = v;

    if (gid < 4 * HDIM) {
        const int gg = gid >> 7, nn = gid & 127;
        const void* bg = (gg == 0) ? bf_ : (gg == 1) ? bi_ : (gg == 2) ? bc_ : bo_;
        if constexpr (FP32) bpk[gid] = ((const float*)bg)[nn];
        else                bpk[gid] = bf2f(((const unsigned short*)bg)[nn]);
    }
}

template <bool FP32>
__global__ __launch_bounds__(512, 4)
void lstm_fused(const void* __restrict__ x_, const void* __restrict__ ws,
                void* __restrict__ out_, const int* __restrict__ flag)
{
    if (*flag != (FP32 ? 1 : 0)) return;   // wrong-dtype variant: uniform exit

    __shared__ __align__(16) unsigned short h_lds[2][MB * HLDS_ST];   // 17408 B
    __shared__ __align__(16) unsigned short x_lds[2][MB * XLDS_ST];   //  5120 B
    __shared__ __align__(16) float          c_lds[MB * CLDS_ST];      // 16896 B

    const int tid  = threadIdx.x;
    const int wv   = tid >> 6;     // wave 0..7: owns output cols [16wv, 16wv+16)
    const int lane = tid & 63;
    const int q    = lane >> 4;    // quad
    const int cc   = lane & 15;
    const int b0   = blockIdx.x * MB;

    const unsigned short* wpk = (const unsigned short*)((const char*)ws + WS_WOFF);
    const float*          bpk = (const float*)((const char*)ws + WS_BOFF);

    // ---- persistent weight B-fragments: 4 gates x 5 ks x 4 VGPR = 80 regs.
    // Loaded once from L2 (20 x dwordx4 per thread); zero in-loop traffic.
    Frag bfr[4][KSTEPS];
    #pragma unroll
    for (int ks = 0; ks < KSTEPS; ++ks)
        #pragma unroll
        for (int g = 0; g < 4; ++g)
            bfr[g][ks].f = *(const short8*)(wpk + (size_t)(wv * KSTEPS + ks) * 2048
                                                + lane * 32 + g * 8);

    float bias_r[4];
    #pragma unroll
    for (int g = 0; g < 4; ++g)
        bias_r[g] = bpk[g * HDIM + wv * 16 + cc];

    // zero h buf0 (h0=0), c (c0=0), x pads (shorts 28..39 stay 0 forever)
    for (int i = tid; i < MB * HLDS_ST; i += 512) h_lds[0][i] = 0;
    for (int i = tid; i < MB * XLDS_ST; i += 512) { x_lds[0][i] = 0; x_lds[1][i] = 0; }
    for (int i = tid; i < MB * CLDS_ST; i += 512) c_lds[i] = 0.0f;

    // x staging: 7 threads/row, 4 elems each -> 28 elems/row (224 of 512 threads)
    auto stage_x = [&](int ts, int buf) {
        if (tid < 224) {
            const int row = tid / 7, sub = tid % 7;
            const size_t off = (size_t)(b0 + row) * (T_STEPS * 28) + ts * 28 + sub * 4;
            Pk4 pk;
            if constexpr (FP32) {
                float4 v = *(const float4*)((const float*)x_ + off);
                pk.s[0] = f2bf(v.x); pk.s[1] = f2bf(v.y);
                pk.s[2] = f2bf(v.z); pk.s[3] = f2bf(v.w);
            } else {
                pk.u2 = *(const uint2*)((const unsigned short*)x_ + off);
            }
            *(uint2*)&x_lds[buf][row * XLDS_ST + sub * 4] = pk.u2;
        }
    };
    stage_x(0, 0);

    __syncthreads();

    int cur = 0;
    #pragma unroll 1
    for (int t = 0; t < T_STEPS; ++t) {
        // prefetch next x tile into the other buffer (no reader until next step)
        if (t + 1 < T_STEPS) stage_x(t + 1, cur ^ 1);

        #pragma unroll
        for (int mt = 0; mt < 2; ++mt) {
            // A fragments: parity double-buffer across ks (8 regs live)
            Frag a[2];
            a[0].f = *(const short8*)&h_lds[cur][(mt * 16 + cc) * HLDS_ST + q * 8];

            floatx4 acc[4];
            #pragma unroll
            for (int g = 0; g < 4; ++g) {
                const float bv = bias_r[g];
                acc[g] = (floatx4){bv, bv, bv, bv};
            }

            #pragma unroll
            for (int ks = 0; ks < KSTEPS; ++ks) {
                if (ks + 1 < KSTEPS) {
                    if (ks + 1 < 4)
                        a[(ks + 1) & 1].f = *(const short8*)
                            &h_lds[cur][(mt * 16 + cc) * HLDS_ST + (ks + 1) * 32 + q * 8];
                    else
                        a[(ks + 1) & 1].f = *(const short8*)
                            &x_lds[cur][(mt * 16 + cc) * XLDS_ST + q * 8];
                }
                #pragma unroll
                for (int g = 0; g < 4; ++g)
                    acc[g] = __builtin_amdgcn_mfma_f32_16x16x32_bf16(
                        a[ks & 1].f, bfr[g][ks].f, acc[g], 0, 0, 0);
            }

            // gates in-register: activations + c,h update (c in LDS, fp32,
            // thread-private addresses -> no extra barrier needed)
            const int j = wv * 16 + cc;
            #pragma unroll
            for (int r = 0; r < 4; ++r) {
                const int mrow = mt * 16 + q * 4 + r;
                const float fv = sigm(acc[0][r]);
                const float iv = sigm(acc[1][r]);
                const float nv = tanh_f(acc[2][r]);
                const float ov = sigm(acc[3][r]);
                const float cn = c_lds[mrow * CLDS_ST + j] * fv + iv * nv;
                c_lds[mrow * CLDS_ST + j] = cn;
                const float hv = ov * tanh_f(cn);
                h_lds[cur ^ 1][mrow * HLDS_ST + j] = f2bf(hv);
                if (t == T_STEPS - 1) {
                    const size_t oi = (size_t)(b0 + mrow) * HDIM + j;
                    if constexpr (FP32) ((float*)out_)[oi] = hv;
                    else                ((unsigned short*)out_)[oi] = f2bf(hv);
                }
            }
        }
        __syncthreads();     // single barrier: publishes h[cur^1] and x[cur^1]
        cur ^= 1;
    }
}

extern "C" void kernel_launch(void* const* d_in, const int* in_sizes, int n_in,
                              void* d_out, int out_size, void* d_ws, size_t ws_size,
                              hipStream_t stream) {
    int* flag = (int*)d_ws;
    detect_dtype<<<dim3(1), dim3(64), 0, stream>>>((const unsigned short*)d_in[1], flag);

    pack_weights<false><<<dim3(320), dim3(256), 0, stream>>>(
        d_in[1], d_in[2], d_in[3], d_in[4], d_in[5], d_in[6], d_in[7], d_in[8], d_ws, flag);
    pack_weights<true><<<dim3(320), dim3(256), 0, stream>>>(
        d_in[1], d_in[2], d_in[3], d_in[4], d_in[5], d_in[6], d_in[7], d_in[8], d_ws, flag);

    lstm_fused<false><<<dim3(65536 / MB), dim3(512), 0, stream>>>(d_in[0], d_ws, d_out, flag);
    lstm_fused<true><<<dim3(65536 / MB), dim3(512), 0, stream>>>(d_in[0], d_ws, d_out, flag);
}